// Round 3
// baseline (4368.315 us; speedup 1.0000x reference)
//
#include <hip/hip_runtime.h>
#include <hip/hip_bf16.h>

#define B 128
#define S 16
#define E 512
#define R 1000
#define K3 1536
#define SCALE 0.04419417382415922f

static __device__ __forceinline__ float sigm(float x) { return 1.f / (1.f + expf(-x)); }

// ---------- block reductions (256 threads) ----------
static __device__ __forceinline__ float brsum(float v, float* sb) {
  int tid = threadIdx.x;
  sb[tid] = v; __syncthreads();
  for (int s = 128; s > 0; s >>= 1) {
    if (tid < s) sb[tid] += sb[tid + s];
    __syncthreads();
  }
  float r = sb[0]; __syncthreads();
  return r;
}
static __device__ __forceinline__ float brmax(float v, float* sb) {
  int tid = threadIdx.x;
  sb[tid] = v; __syncthreads();
  for (int s = 128; s > 0; s >>= 1) {
    if (tid < s) sb[tid] = fmaxf(sb[tid], sb[tid + s]);
    __syncthreads();
  }
  float r = sb[0]; __syncthreads();
  return r;
}

// ---------- embed gather ----------
__global__ __launch_bounds__(256) void k_embed(const int* __restrict__ tokens,
                                               const float* __restrict__ emb,
                                               float* __restrict__ X) {
  int idx = blockIdx.x * 256 + threadIdx.x;
  if (idx >= B * S * E) return;
  int row = idx >> 9;          // b*16+i
  int e = idx & (E - 1);
  int tok = tokens[row];
  X[idx] = emb[(size_t)tok * E + e];
}

// ---------- tiled GEMM: C[m,n] = scale * sum_k A[row(m),k] * W[n,k] + bias[n]
// A: fp32, row(m) offset = (m/rpb)*strideB + (m%rpb)*E ; W: (N,K=512) row-major fp32
__global__ __launch_bounds__(256) void k_gemm(const float* __restrict__ A, int rpb, int strideB,
                                              int M, const float* __restrict__ W, int N,
                                              const float* __restrict__ bias, float scale,
                                              float* __restrict__ C, int ldc) {
  __shared__ float As[16][64];
  __shared__ float Ws[16][64];
  int tid = threadIdx.x;
  int mBase = blockIdx.y * 64;
  int nBase = blockIdx.x * 64;
  int tx = tid & 15, ty = tid >> 4;
  int li = tid & 63;
  int lk = (tid >> 6) * 4;
  float acc[4][4] = {{0.f, 0.f, 0.f, 0.f}, {0.f, 0.f, 0.f, 0.f},
                     {0.f, 0.f, 0.f, 0.f}, {0.f, 0.f, 0.f, 0.f}};
  int m = mBase + li;
  int aoff = -1;
  if (m < M) aoff = (m / rpb) * strideB + (m % rpb) * E;
  int n = nBase + li;

  for (int k0 = 0; k0 < E; k0 += 16) {
    float4 av = make_float4(0.f, 0.f, 0.f, 0.f);
    if (aoff >= 0) av = *(const float4*)(A + aoff + k0 + lk);
    As[lk + 0][li] = av.x; As[lk + 1][li] = av.y;
    As[lk + 2][li] = av.z; As[lk + 3][li] = av.w;
    float4 wv = make_float4(0.f, 0.f, 0.f, 0.f);
    if (n < N) wv = *(const float4*)(W + (size_t)n * E + k0 + lk);
    Ws[lk + 0][li] = wv.x; Ws[lk + 1][li] = wv.y;
    Ws[lk + 2][li] = wv.z; Ws[lk + 3][li] = wv.w;
    __syncthreads();
#pragma unroll
    for (int k = 0; k < 16; ++k) {
      float4 a4 = *(const float4*)&As[k][ty * 4];
      float4 w4 = *(const float4*)&Ws[k][tx * 4];
      acc[0][0] = fmaf(a4.x, w4.x, acc[0][0]); acc[0][1] = fmaf(a4.x, w4.y, acc[0][1]);
      acc[0][2] = fmaf(a4.x, w4.z, acc[0][2]); acc[0][3] = fmaf(a4.x, w4.w, acc[0][3]);
      acc[1][0] = fmaf(a4.y, w4.x, acc[1][0]); acc[1][1] = fmaf(a4.y, w4.y, acc[1][1]);
      acc[1][2] = fmaf(a4.y, w4.z, acc[1][2]); acc[1][3] = fmaf(a4.y, w4.w, acc[1][3]);
      acc[2][0] = fmaf(a4.z, w4.x, acc[2][0]); acc[2][1] = fmaf(a4.z, w4.y, acc[2][1]);
      acc[2][2] = fmaf(a4.z, w4.z, acc[2][2]); acc[2][3] = fmaf(a4.z, w4.w, acc[2][3]);
      acc[3][0] = fmaf(a4.w, w4.x, acc[3][0]); acc[3][1] = fmaf(a4.w, w4.y, acc[3][1]);
      acc[3][2] = fmaf(a4.w, w4.z, acc[3][2]); acc[3][3] = fmaf(a4.w, w4.w, acc[3][3]);
    }
    __syncthreads();
  }
#pragma unroll
  for (int r = 0; r < 4; ++r) {
    int mm = mBase + ty * 4 + r;
    if (mm >= M) continue;
#pragma unroll
    for (int c = 0; c < 4; ++c) {
      int nn = nBase + tx * 4 + c;
      if (nn >= N) continue;
      float v = acc[r][c] * scale;
      if (bias) v += bias[nn];
      C[(size_t)mm * ldc + nn] = v;
    }
  }
}

// ---------- GRU pointwise ----------
__global__ __launch_bounds__(256) void k_h1(const float* __restrict__ GI,
                                            const float* __restrict__ bhh,
                                            float* __restrict__ H1, int L) {
  int P = L - 1;
  int m = blockIdx.x;
  int b = m / P, i = m - b * P;
  const float* gi = GI + (size_t)(b * L + i) * K3;
  float* h = H1 + (size_t)m * E;
  for (int e = threadIdx.x; e < E; e += 256) {
    float r = sigm(gi[e] + bhh[e]);
    float z = sigm(gi[E + e] + bhh[E + e]);
    float n = tanhf(gi[2 * E + e] + r * bhh[2 * E + e]);
    h[e] = (1.f - z) * n;
  }
}

__global__ __launch_bounds__(256) void k_pairs(const float* __restrict__ GI,
                                               const float* __restrict__ GH,
                                               const float* __restrict__ H1,
                                               float* __restrict__ PAIRS, int L) {
  int P = L - 1;
  int m = blockIdx.x;
  int b = m / P, i = m - b * P;
  const float* gi = GI + (size_t)(b * L + i + 1) * K3;
  const float* gh = GH + (size_t)m * K3;
  const float* h = H1 + (size_t)m * E;
  float* p = PAIRS + (size_t)m * E;
  for (int e = threadIdx.x; e < E; e += 256) {
    float r = sigm(gi[e] + gh[e]);
    float z = sigm(gi[E + e] + gh[E + e]);
    float n = tanhf(gi[2 * E + e] + r * gh[2 * E + e]);
    p[e] = (1.f - z) * n + z * h[e];
  }
}

// ---------- fc score + argmax (first max, matching jnp.argmax) ----------
__global__ __launch_bounds__(256) void k_fc_argmax(const float* __restrict__ PAIRS,
                                                   const float* __restrict__ wfc,
                                                   const float* __restrict__ bfc,
                                                   int L, int* __restrict__ SEL) {
  __shared__ float sb[256];
  __shared__ float sc[16];
  int b = blockIdx.x, tid = threadIdx.x;
  int P = L - 1;
  for (int i = 0; i < P; ++i) {
    const float* p = PAIRS + (size_t)(b * P + i) * E;
    float part = 0.f;
    for (int e = tid; e < E; e += 256) part += p[e] * wfc[e];
    float d = brsum(part, sb);
    if (tid == 0) sc[i] = sigm(d + bfc[0]);
  }
  __syncthreads();
  if (tid == 0) {
    float best = sc[0]; int bi = 0;
    for (int i = 1; i < P; ++i)
      if (sc[i] > best) { best = sc[i]; bi = i; }
    SEL[b] = bi;
  }
}

__global__ __launch_bounds__(256) void k_gather(const float* __restrict__ PAIRS,
                                                const int* __restrict__ SEL, int L,
                                                float* __restrict__ SP) {
  int b = blockIdx.x;
  int sel = SEL ? SEL[b] : 0;
  int P = L - 1;
  const float* src = PAIRS + (size_t)(b * P + sel) * E;
  float* dst = SP + (size_t)b * E;
  for (int e = threadIdx.x; e < E; e += 256) dst[e] = src[e];
}

// ---------- softmax / entropy; optionally overwrite SC with probs ----------
__global__ __launch_bounds__(256) void k_softmax(float* __restrict__ SC,
                                                 const float* __restrict__ Q,
                                                 const float* __restrict__ KL,
                                                 float* __restrict__ LOSS, int t, int writeProb) {
  __shared__ float sb[256];
  int b = blockIdx.x, tid = threadIdx.x;
  const float* q = Q + (size_t)b * E;
  const float* kl = KL + (size_t)b * E;
  float part = 0.f;
  for (int e = tid; e < E; e += 256) part += q[e] * kl[e];
  float last = brsum(part, sb) * SCALE;
  float* s = SC + (size_t)b * (R + 1);
  if (tid == 0) s[R] = last;
  __syncthreads();
  float mx = -1e30f;
  for (int j = tid; j <= R; j += 256) mx = fmaxf(mx, s[j]);
  mx = brmax(mx, sb);
  float z = 0.f, s1 = 0.f;
  for (int j = tid; j <= R; j += 256) {
    float sj = s[j];
    float e = expf(sj - mx);
    z += e; s1 += e * sj;
  }
  z = brsum(z, sb);
  s1 = brsum(s1, sb);
  if (tid == 0) LOSS[b * 16 + t] = mx + logf(z) - s1 / z;
  if (writeProb) {
    float inv = 1.f / z;
    for (int j = tid; j <= R; j += 256) s[j] = expf(s[j] - mx) * inv;
  }
}

// ---------- merged = prob[:R] @ emb[:R] + prob[R] * pair ----------
__global__ __launch_bounds__(256) void k_merged(const float* __restrict__ PR,
                                                const float* __restrict__ emb,
                                                const float* __restrict__ SP,
                                                float* __restrict__ MG) {
  __shared__ float p[R + 1];
  int b = blockIdx.x;
  int e = blockIdx.y * 256 + threadIdx.x;
  for (int j = threadIdx.x; j <= R; j += 256) p[j] = PR[(size_t)b * (R + 1) + j];
  __syncthreads();
  float acc = 0.f;
  const float* em = emb + e;
#pragma unroll 8
  for (int j = 0; j < R; ++j) acc = fmaf(p[j], em[(size_t)j * E], acc);
  acc = fmaf(p[R], SP[(size_t)b * E + e], acc);
  MG[(size_t)b * E + e] = acc;
}

// ---------- merge/shift into next x buffer ----------
__global__ __launch_bounds__(256) void k_shift(const float* __restrict__ Xold,
                                               const float* __restrict__ MG,
                                               const int* __restrict__ SEL, int L,
                                               float* __restrict__ Xnew) {
  int Lnew = L - 1;
  int m = blockIdx.x;  // b*Lnew + i
  int b = m / Lnew, i = m - b * Lnew;
  int sel = SEL[b];
  const float* src;
  if (i == sel) src = MG + (size_t)b * E;
  else src = Xold + (size_t)(b * S + (i > sel ? i + 1 : i)) * E;
  float* dst = Xnew + (size_t)(b * S + i) * E;
  for (int e = threadIdx.x; e < E; e += 256) dst[e] = src[e];
}

// ---------- final write (fp32 out: scores then losses, flat) ----------
__global__ __launch_bounds__(256) void k_writeout(const float* __restrict__ SC,
                                                  const float* __restrict__ LOSS,
                                                  float* __restrict__ out) {
  int idx = blockIdx.x * 256 + threadIdx.x;
  const int NS = B * (R + 1);
  if (idx < NS) {
    out[idx] = SC[idx];
  } else if (idx < NS + B * 16) {
    int r = idx - NS;
    int t = r & 15;
    out[idx] = (t == 14) ? 0.f : LOSS[r];
  }
}

extern "C" void kernel_launch(void* const* d_in, const int* in_sizes, int n_in,
                              void* d_out, int out_size, void* d_ws, size_t ws_size,
                              hipStream_t stream) {
  (void)in_sizes; (void)n_in; (void)out_size; (void)ws_size;
  const int* tokens = (const int*)d_in[0];
  const float* emb = (const float*)d_in[1];
  const float* W_ih = (const float*)d_in[2];
  const float* W_hh = (const float*)d_in[3];
  const float* b_ih = (const float*)d_in[4];
  const float* b_hh = (const float*)d_in[5];
  const float* w_fc = (const float*)d_in[6];
  const float* b_fc = (const float*)d_in[7];
  const float* Wq = (const float*)d_in[8];
  const float* bq = (const float*)d_in[9];
  const float* Wk = (const float*)d_in[10];
  const float* bk = (const float*)d_in[11];
  float* out = (float*)d_out;

  float* ws = (float*)d_ws;
  size_t o = 0;
  float* X0 = ws + o;    o += (size_t)B * S * E;
  float* X1 = ws + o;    o += (size_t)B * S * E;
  float* GI = ws + o;    o += (size_t)B * S * K3;
  float* H1 = ws + o;    o += (size_t)B * 15 * E;
  float* GH = ws + o;    o += (size_t)B * 15 * K3;
  float* PAIRS = ws + o; o += (size_t)B * 15 * E;
  float* KREL = ws + o;  o += (size_t)R * E;
  float* Q = ws + o;     o += (size_t)B * E;
  float* KL = ws + o;    o += (size_t)B * E;
  float* SP = ws + o;    o += (size_t)B * E;
  float* SC = ws + o;    o += (size_t)B * (R + 1);
  float* MG = ws + o;    o += (size_t)B * E;
  float* LOSS = ws + o;  o += (size_t)B * 16;
  int* SEL = (int*)(ws + o);

  k_embed<<<(B * S * E + 255) / 256, 256, 0, stream>>>(tokens, emb, X0);
  // K_rel = emb[:R] @ Wk^T + bk  (batch-invariant, once)
  k_gemm<<<dim3(E / 64, (R + 63) / 64), 256, 0, stream>>>(
      emb, R, 0, R, Wk, E, bk, 1.f, KREL, E);

  float* Xc = X0; float* Xn = X1;
  for (int t = 0; t < 14; ++t) {
    int L = 16 - t;
    int P = L - 1;
    int M1 = B * L, M2 = B * P;
    k_gemm<<<dim3(K3 / 64, (M1 + 63) / 64), 256, 0, stream>>>(
        Xc, L, S * E, M1, W_ih, K3, b_ih, 1.f, GI, K3);
    k_h1<<<M2, 256, 0, stream>>>(GI, b_hh, H1, L);
    k_gemm<<<dim3(K3 / 64, (M2 + 63) / 64), 256, 0, stream>>>(
        H1, M2, 0, M2, W_hh, K3, b_hh, 1.f, GH, K3);
    k_pairs<<<M2, 256, 0, stream>>>(GI, GH, H1, PAIRS, L);
    k_fc_argmax<<<B, 256, 0, stream>>>(PAIRS, w_fc, b_fc, L, SEL);
    k_gather<<<B, 256, 0, stream>>>(PAIRS, SEL, L, SP);
    k_gemm<<<dim3(E / 64, (B + 63) / 64), 256, 0, stream>>>(
        SP, B, 0, B, Wq, E, bq, 1.f, Q, E);
    k_gemm<<<dim3(E / 64, (B + 63) / 64), 256, 0, stream>>>(
        SP, B, 0, B, Wk, E, bk, 1.f, KL, E);
    k_gemm<<<dim3((R + 63) / 64, (B + 63) / 64), 256, 0, stream>>>(
        Q, B, 0, B, KREL, R, (const float*)nullptr, SCALE, SC, R + 1);
    k_softmax<<<B, 256, 0, stream>>>(SC, Q, KL, LOSS, t, 1);
    k_merged<<<dim3(B, 2), 256, 0, stream>>>(SC, emb, SP, MG);
    k_shift<<<B * P, 256, 0, stream>>>(Xc, MG, SEL, L, Xn);
    float* tmp = Xc; Xc = Xn; Xn = tmp;
  }
  // final GRU step (L==2 branch)
  {
    int L = 2, M1 = B * 2, M2 = B;
    k_gemm<<<dim3(K3 / 64, (M1 + 63) / 64), 256, 0, stream>>>(
        Xc, L, S * E, M1, W_ih, K3, b_ih, 1.f, GI, K3);
    k_h1<<<M2, 256, 0, stream>>>(GI, b_hh, H1, L);
    k_gemm<<<dim3(K3 / 64, (M2 + 63) / 64), 256, 0, stream>>>(
        H1, M2, 0, M2, W_hh, K3, b_hh, 1.f, GH, K3);
    k_pairs<<<M2, 256, 0, stream>>>(GI, GH, H1, PAIRS, L);
    k_gather<<<B, 256, 0, stream>>>(PAIRS, (const int*)nullptr, L, SP);
    k_gemm<<<dim3(E / 64, (B + 63) / 64), 256, 0, stream>>>(
        SP, B, 0, B, Wq, E, bq, 1.f, Q, E);
    k_gemm<<<dim3(E / 64, (B + 63) / 64), 256, 0, stream>>>(
        SP, B, 0, B, Wk, E, bk, 1.f, KL, E);
    k_gemm<<<dim3((R + 63) / 64, (B + 63) / 64), 256, 0, stream>>>(
        Q, B, 0, B, KREL, R, (const float*)nullptr, SCALE, SC, R + 1);
    k_softmax<<<B, 256, 0, stream>>>(SC, Q, KL, LOSS, 15, 0);
  }
  k_writeout<<<(B * (R + 1) + B * 16 + 255) / 256, 256, 0, stream>>>(SC, LOSS, out);
}

// Round 4
// 4344.914 us; speedup vs baseline: 1.0054x; 1.0054x over previous
//
#include <hip/hip_runtime.h>
#include <hip/hip_bf16.h>

#define B 128
#define S 16
#define E 512
#define R 1000
#define K3 1536
#define NW0 1920   // init worklist: 128 b * 15 pairs
#define NWS 256    // per-step worklist: 128 b * 2 entries
#define SCALE 0.04419417382415922f

static __device__ __forceinline__ float sigm(float x) { return 1.f / (1.f + expf(-x)); }

// ---------- block reductions (256 threads) ----------
static __device__ __forceinline__ float brsum(float v, float* sb) {
  int tid = threadIdx.x;
  sb[tid] = v; __syncthreads();
  for (int s = 128; s > 0; s >>= 1) {
    if (tid < s) sb[tid] += sb[tid + s];
    __syncthreads();
  }
  float r = sb[0]; __syncthreads();
  return r;
}
static __device__ __forceinline__ float brmax(float v, float* sb) {
  int tid = threadIdx.x;
  sb[tid] = v; __syncthreads();
  for (int s = 128; s > 0; s >>= 1) {
    if (tid < s) sb[tid] = fmaxf(sb[tid], sb[tid + s]);
    __syncthreads();
  }
  float r = sb[0]; __syncthreads();
  return r;
}

// ---------- embed gather: X[b][slot][e], slot=i at init ----------
__global__ __launch_bounds__(256) void k_embed(const int* __restrict__ tokens,
                                               const float* __restrict__ emb,
                                               float* __restrict__ X) {
  int idx = blockIdx.x * 256 + threadIdx.x;
  if (idx >= B * S * E) return;
  int row = idx >> 9;
  int e = idx & (E - 1);
  int tok = tokens[row];
  X[idx] = emb[(size_t)tok * E + e];
}

// ---------- init: pos identity + full worklist ----------
__global__ __launch_bounds__(256) void k_initwl(int* __restrict__ pos,
                                                int* __restrict__ wlb,
                                                int* __restrict__ wlL,
                                                int* __restrict__ wlR) {
  int idx = blockIdx.x * 256 + threadIdx.x;
  if (idx < B * 16) pos[idx] = idx & 15;
  if (idx < NW0) {
    wlb[idx] = idx / 15;
    int i = idx % 15;
    wlL[idx] = i;
    wlR[idx] = i + 1;
  }
}

// ---------- tiled GEMM, K=512 fixed:
// C[row,n] = scale * sum_k A[m*strideB + k] * Wsel[n][k] + bias_sel[n]
// Wsel = (W2 && n>=512) ? W2[n-512] : W1[n]; row = cdst ? cdst[m] : m
__global__ __launch_bounds__(256) void k_gemm(const float* __restrict__ A, int strideB, int M,
                                              const float* __restrict__ W1,
                                              const float* __restrict__ W2, int N,
                                              const float* __restrict__ b1,
                                              const float* __restrict__ b2, float scale,
                                              float* __restrict__ C, int ldc,
                                              const int* __restrict__ cdst) {
  __shared__ float As[16][64];
  __shared__ float Ws[16][64];
  int tid = threadIdx.x;
  int mBase = blockIdx.y * 64;
  int nBase = blockIdx.x * 64;
  int tx = tid & 15, ty = tid >> 4;
  int li = tid & 63;
  int lk = (tid >> 6) * 4;
  float acc[4][4] = {{0.f,0.f,0.f,0.f},{0.f,0.f,0.f,0.f},{0.f,0.f,0.f,0.f},{0.f,0.f,0.f,0.f}};
  int m = mBase + li;
  long aoff = (m < M) ? (long)m * strideB : -1;
  int n = nBase + li;
  const float* Wrow = nullptr;
  if (n < N) Wrow = (W2 && n >= 512) ? (W2 + (size_t)(n - 512) * E) : (W1 + (size_t)n * E);

  for (int k0 = 0; k0 < E; k0 += 16) {
    float4 av = make_float4(0.f, 0.f, 0.f, 0.f);
    if (aoff >= 0) av = *(const float4*)(A + aoff + k0 + lk);
    As[lk + 0][li] = av.x; As[lk + 1][li] = av.y;
    As[lk + 2][li] = av.z; As[lk + 3][li] = av.w;
    float4 wv = make_float4(0.f, 0.f, 0.f, 0.f);
    if (Wrow) wv = *(const float4*)(Wrow + k0 + lk);
    Ws[lk + 0][li] = wv.x; Ws[lk + 1][li] = wv.y;
    Ws[lk + 2][li] = wv.z; Ws[lk + 3][li] = wv.w;
    __syncthreads();
#pragma unroll
    for (int k = 0; k < 16; ++k) {
      float4 a4 = *(const float4*)&As[k][ty * 4];
      float4 w4 = *(const float4*)&Ws[k][tx * 4];
      acc[0][0] = fmaf(a4.x, w4.x, acc[0][0]); acc[0][1] = fmaf(a4.x, w4.y, acc[0][1]);
      acc[0][2] = fmaf(a4.x, w4.z, acc[0][2]); acc[0][3] = fmaf(a4.x, w4.w, acc[0][3]);
      acc[1][0] = fmaf(a4.y, w4.x, acc[1][0]); acc[1][1] = fmaf(a4.y, w4.y, acc[1][1]);
      acc[1][2] = fmaf(a4.y, w4.z, acc[1][2]); acc[1][3] = fmaf(a4.y, w4.w, acc[1][3]);
      acc[2][0] = fmaf(a4.z, w4.x, acc[2][0]); acc[2][1] = fmaf(a4.z, w4.y, acc[2][1]);
      acc[2][2] = fmaf(a4.z, w4.z, acc[2][2]); acc[2][3] = fmaf(a4.z, w4.w, acc[2][3]);
      acc[3][0] = fmaf(a4.w, w4.x, acc[3][0]); acc[3][1] = fmaf(a4.w, w4.y, acc[3][1]);
      acc[3][2] = fmaf(a4.w, w4.z, acc[3][2]); acc[3][3] = fmaf(a4.w, w4.w, acc[3][3]);
    }
    __syncthreads();
  }
#pragma unroll
  for (int r = 0; r < 4; ++r) {
    int mm = mBase + ty * 4 + r;
    if (mm >= M) continue;
    size_t crow = (size_t)(cdst ? cdst[mm] : mm) * ldc;
#pragma unroll
    for (int c = 0; c < 4; ++c) {
      int nn = nBase + tx * 4 + c;
      if (nn >= N) continue;
      float v = acc[r][c] * scale;
      if (b1) v += (b2 && nn >= 512) ? b2[nn - 512] : b1[nn];
      C[crow + nn] = v;
    }
  }
}

// ---------- h1 for worklist entries: H1C[w] = f(GI[b][lslot]) ----------
__global__ __launch_bounds__(256) void k_h1c(const int* __restrict__ wlb,
                                             const int* __restrict__ wlL,
                                             const float* __restrict__ GI,
                                             const float* __restrict__ bhh,
                                             float* __restrict__ H1C) {
  int w = blockIdx.x;
  const float* gi = GI + (size_t)(wlb[w] * 16 + wlL[w]) * K3;
  float* h = H1C + (size_t)w * E;
  for (int e = threadIdx.x; e < E; e += 256) {
    float r = sigm(gi[e] + bhh[e]);
    float z = sigm(gi[E + e] + bhh[E + e]);
    float n = tanhf(gi[2 * E + e] + r * bhh[2 * E + e]);
    h[e] = (1.f - z) * n;
  }
}

// ---------- pair + fc score for worklist entries ----------
__global__ __launch_bounds__(256) void k_pairc(const int* __restrict__ wlb,
                                               const int* __restrict__ wlL,
                                               const int* __restrict__ wlR,
                                               const float* __restrict__ GI,
                                               const float* __restrict__ GHC,
                                               const float* __restrict__ H1C,
                                               const float* __restrict__ wfc,
                                               const float* __restrict__ bfc,
                                               float* __restrict__ PAIR,
                                               float* __restrict__ SCR) {
  __shared__ float sb[256];
  int w = blockIdx.x, tid = threadIdx.x;
  int b = wlb[w], ls = wlL[w], rs = wlR[w];
  const float* gi = GI + (size_t)(b * 16 + rs) * K3;
  const float* gh = GHC + (size_t)w * K3;
  const float* h = H1C + (size_t)w * E;
  float* p = PAIR + (size_t)(b * 16 + ls) * E;
  float part = 0.f;
  for (int e = tid; e < E; e += 256) {
    float r = sigm(gi[e] + gh[e]);
    float z = sigm(gi[E + e] + gh[E + e]);
    float n = tanhf(gi[2 * E + e] + r * gh[2 * E + e]);
    float pv = (1.f - z) * n + z * h[e];
    p[e] = pv;
    part += pv * wfc[e];
  }
  float d = brsum(part, sb);
  if (tid == 0) SCR[b * 16 + ls] = sigm(d + bfc[0]);
}

// ---------- argmax + gather + pos/worklist update ----------
__global__ __launch_bounds__(256) void k_sel(const float* __restrict__ SCR,
                                             const float* __restrict__ PAIR,
                                             int* __restrict__ pos, int P,
                                             float* __restrict__ SP,
                                             int* __restrict__ xdst,
                                             int* __restrict__ wlb,
                                             int* __restrict__ wlL,
                                             int* __restrict__ wlR) {
  __shared__ int s_m;
  int b = blockIdx.x, tid = threadIdx.x;
  if (tid == 0) {
    int L = P + 1;
    int lp[16];
    for (int i = 0; i < L; ++i) lp[i] = pos[b * 16 + i];
    float best = -1e30f; int sel = 0;
    for (int i = 0; i < P; ++i) {
      float v = SCR[b * 16 + lp[i]];
      if (v > best) { best = v; sel = i; }
    }
    int r1i = (sel + 2 < L) ? sel + 2 : L - 1;
    int l1 = lp[sel], r1 = lp[r1i];
    int l0 = (sel > 0) ? lp[sel - 1] : l1;
    int r0 = (sel > 0) ? lp[sel] : r1;
    wlb[2 * b] = b;     wlL[2 * b] = l0;     wlR[2 * b] = r0;
    wlb[2 * b + 1] = b; wlL[2 * b + 1] = l1; wlR[2 * b + 1] = r1;
    xdst[b] = b * 16 + lp[sel];
    for (int i = sel + 1; i < L - 1; ++i) pos[b * 16 + i] = lp[i + 1];
    s_m = lp[sel];
  }
  __syncthreads();
  int ms = s_m;
  const float* src = PAIR + (size_t)(b * 16 + ms) * E;
  float* dst = SP + (size_t)b * E;
  for (int e = tid; e < E; e += 256) dst[e] = src[e];
}

// ---------- final gather: SP = PAIR[b][pos[0]] ----------
__global__ __launch_bounds__(256) void k_finsel(const float* __restrict__ PAIR,
                                                const int* __restrict__ pos,
                                                float* __restrict__ SP) {
  int b = blockIdx.x;
  const float* src = PAIR + (size_t)(b * 16 + pos[b * 16]) * E;
  float* dst = SP + (size_t)b * E;
  for (int e = threadIdx.x; e < E; e += 256) dst[e] = src[e];
}

// ---------- softmax / entropy over SC row; prob in place if writeProb ----------
__global__ __launch_bounds__(256) void k_softmax(float* __restrict__ SC,
                                                 const float* __restrict__ QK,
                                                 float* __restrict__ LOSS, int t, int writeProb) {
  __shared__ float sb[256];
  int b = blockIdx.x, tid = threadIdx.x;
  const float* q = QK + (size_t)b * 1024;
  const float* kl = q + 512;
  float part = 0.f;
  for (int e = tid; e < E; e += 256) part += q[e] * kl[e];
  float last = brsum(part, sb) * SCALE;
  float* s = SC + (size_t)b * (R + 1);
  if (tid == 0) s[R] = last;
  __syncthreads();
  float mx = -1e30f;
  for (int j = tid; j <= R; j += 256) mx = fmaxf(mx, s[j]);
  mx = brmax(mx, sb);
  float z = 0.f, s1 = 0.f;
  for (int j = tid; j <= R; j += 256) {
    float sj = s[j];
    float e = expf(sj - mx);
    z += e; s1 += e * sj;
  }
  z = brsum(z, sb);
  s1 = brsum(s1, sb);
  if (tid == 0) LOSS[b * 16 + t] = mx + logf(z) - s1 / z;
  if (writeProb) {
    float inv = 1.f / z;
    for (int j = tid; j <= R; j += 256) s[j] = expf(s[j] - mx) * inv;
  }
}

// ---------- merged gemm (B non-transposed): MROW[m] = prob[m,:R]@emb + prob[m,R]*SP[m]
__global__ __launch_bounds__(256) void k_merged(const float* __restrict__ SC,
                                                const float* __restrict__ emb,
                                                const float* __restrict__ SP,
                                                float* __restrict__ MROW) {
  __shared__ float As[16][64];
  __shared__ float Ws[16][64];
  int tid = threadIdx.x;
  int mBase = blockIdx.y * 64;
  int nBase = blockIdx.x * 64;
  int tx = tid & 15, ty = tid >> 4;
  int li = tid & 63;
  int lk = (tid >> 6) * 4;
  float acc[4][4] = {{0.f,0.f,0.f,0.f},{0.f,0.f,0.f,0.f},{0.f,0.f,0.f,0.f},{0.f,0.f,0.f,0.f}};
  int m = mBase + li;                       // m < 128 always (grid sized)
  int wr = tid >> 6;                        // 0..3 -> k row group
  for (int k0 = 0; k0 < R; k0 += 16) {
    float4 av = make_float4(0.f, 0.f, 0.f, 0.f);
    if (k0 + lk + 3 < R) av = *(const float4*)(SC + (size_t)m * (R + 1) + k0 + lk);
    else {
      float tmp[4];
      for (int j = 0; j < 4; ++j) tmp[j] = (k0 + lk + j < R) ? SC[(size_t)m * (R + 1) + k0 + lk + j] : 0.f;
      av = make_float4(tmp[0], tmp[1], tmp[2], tmp[3]);
    }
    As[lk + 0][li] = av.x; As[lk + 1][li] = av.y;
    As[lk + 2][li] = av.z; As[lk + 3][li] = av.w;
    // stage emb[k][n]: thread -> rows wr*4..+3, col li
#pragma unroll
    for (int j = 0; j < 4; ++j) {
      int kk = k0 + wr * 4 + j;
      Ws[wr * 4 + j][li] = (kk < R) ? emb[(size_t)kk * E + nBase + li] : 0.f;
    }
    __syncthreads();
#pragma unroll
    for (int k = 0; k < 16; ++k) {
      float4 a4 = *(const float4*)&As[k][ty * 4];
      float4 w4 = *(const float4*)&Ws[k][tx * 4];
      acc[0][0] = fmaf(a4.x, w4.x, acc[0][0]); acc[0][1] = fmaf(a4.x, w4.y, acc[0][1]);
      acc[0][2] = fmaf(a4.x, w4.z, acc[0][2]); acc[0][3] = fmaf(a4.x, w4.w, acc[0][3]);
      acc[1][0] = fmaf(a4.y, w4.x, acc[1][0]); acc[1][1] = fmaf(a4.y, w4.y, acc[1][1]);
      acc[1][2] = fmaf(a4.y, w4.z, acc[1][2]); acc[1][3] = fmaf(a4.y, w4.w, acc[1][3]);
      acc[2][0] = fmaf(a4.z, w4.x, acc[2][0]); acc[2][1] = fmaf(a4.z, w4.y, acc[2][1]);
      acc[2][2] = fmaf(a4.z, w4.z, acc[2][2]); acc[2][3] = fmaf(a4.z, w4.w, acc[2][3]);
      acc[3][0] = fmaf(a4.w, w4.x, acc[3][0]); acc[3][1] = fmaf(a4.w, w4.y, acc[3][1]);
      acc[3][2] = fmaf(a4.w, w4.z, acc[3][2]); acc[3][3] = fmaf(a4.w, w4.w, acc[3][3]);
    }
    __syncthreads();
  }
#pragma unroll
  for (int r = 0; r < 4; ++r) {
    int mm = mBase + ty * 4 + r;
    float probR = SC[(size_t)mm * (R + 1) + R];
#pragma unroll
    for (int c = 0; c < 4; ++c) {
      int nn = nBase + tx * 4 + c;
      float v = acc[r][c] + probR * SP[(size_t)mm * E + nn];
      MROW[(size_t)mm * E + nn] = v;
    }
  }
}

// ---------- final write (fp32 out: scores then losses, flat) ----------
__global__ __launch_bounds__(256) void k_writeout(const float* __restrict__ SC,
                                                  const float* __restrict__ LOSS,
                                                  float* __restrict__ out) {
  int idx = blockIdx.x * 256 + threadIdx.x;
  const int NS = B * (R + 1);
  if (idx < NS) {
    out[idx] = SC[idx];
  } else if (idx < NS + B * 16) {
    int r = idx - NS;
    int t = r & 15;
    out[idx] = (t == 14) ? 0.f : LOSS[r];
  }
}

extern "C" void kernel_launch(void* const* d_in, const int* in_sizes, int n_in,
                              void* d_out, int out_size, void* d_ws, size_t ws_size,
                              hipStream_t stream) {
  (void)in_sizes; (void)n_in; (void)out_size; (void)ws_size;
  const int* tokens = (const int*)d_in[0];
  const float* emb = (const float*)d_in[1];
  const float* W_ih = (const float*)d_in[2];
  const float* W_hh = (const float*)d_in[3];
  const float* b_ih = (const float*)d_in[4];
  const float* b_hh = (const float*)d_in[5];
  const float* w_fc = (const float*)d_in[6];
  const float* b_fc = (const float*)d_in[7];
  const float* Wq = (const float*)d_in[8];
  const float* bq = (const float*)d_in[9];
  const float* Wk = (const float*)d_in[10];
  const float* bk = (const float*)d_in[11];
  float* out = (float*)d_out;

  float* ws = (float*)d_ws;
  size_t o = 0;
  float* X = ws + o;     o += (size_t)B * 16 * E;      // init only
  float* GI = ws + o;    o += (size_t)B * 16 * K3;     // slot-indexed gi cache
  float* PAIR = ws + o;  o += (size_t)B * 16 * E;      // keyed by left slot
  float* SCR = ws + o;   o += (size_t)B * 16;          // fc scores by left slot
  float* H1C = ws + o;   o += (size_t)NW0 * E;
  float* GHC = ws + o;   o += (size_t)NW0 * K3;
  float* KREL = ws + o;  o += (size_t)R * E;
  float* QK = ws + o;    o += (size_t)B * 1024;
  float* SP = ws + o;    o += (size_t)B * E;
  float* SC = ws + o;    o += (size_t)B * (R + 1);
  float* MROW = ws + o;  o += (size_t)B * E;
  float* LOSS = ws + o;  o += (size_t)B * 16;
  int* pos = (int*)(ws + o);  o += B * 16;
  int* wlb = (int*)(ws + o);  o += NW0;
  int* wlL = (int*)(ws + o);  o += NW0;
  int* wlR = (int*)(ws + o);  o += NW0;
  int* xdst = (int*)(ws + o); o += B;

  // ---- setup ----
  k_embed<<<(B * S * E + 255) / 256, 256, 0, stream>>>(tokens, emb, X);
  k_initwl<<<8, 256, 0, stream>>>(pos, wlb, wlL, wlR);
  // K_rel = emb[:R] @ Wk^T + bk
  k_gemm<<<dim3(8, 16), 256, 0, stream>>>(emb, E, R, Wk, nullptr, E, bk, nullptr, 1.f,
                                          KREL, E, nullptr);
  // full GI over all 2048 slot-rows
  k_gemm<<<dim3(24, 32), 256, 0, stream>>>(X, E, B * 16, W_ih, nullptr, K3, b_ih, nullptr,
                                           1.f, GI, K3, nullptr);
  // full pair init (worklist = all 1920 adjacent pairs)
  k_h1c<<<NW0, 256, 0, stream>>>(wlb, wlL, GI, b_hh, H1C);
  k_gemm<<<dim3(24, 30), 256, 0, stream>>>(H1C, E, NW0, W_hh, nullptr, K3, b_hh, nullptr,
                                           1.f, GHC, K3, nullptr);
  k_pairc<<<NW0, 256, 0, stream>>>(wlb, wlL, wlR, GI, GHC, H1C, w_fc, b_fc, PAIR, SCR);

  // ---- 14 merge steps ----
  for (int t = 0; t < 14; ++t) {
    int P = 15 - t;
    k_sel<<<B, 256, 0, stream>>>(SCR, PAIR, pos, P, SP, xdst, wlb, wlL, wlR);
    // q | k_last fused: QK[b] = [Wq·sp+bq , Wk·sp+bk]
    k_gemm<<<dim3(16, 2), 256, 0, stream>>>(SP, E, B, Wq, Wk, 1024, bq, bk, 1.f,
                                            QK, 1024, nullptr);
    // scores vs KREL
    k_gemm<<<dim3(16, 2), 256, 0, stream>>>(QK, 1024, B, KREL, nullptr, R, nullptr, nullptr,
                                            SCALE, SC, R + 1, nullptr);
    k_softmax<<<B, 256, 0, stream>>>(SC, QK, LOSS, t, 1);
    // merged row (compact MROW)
    k_merged<<<dim3(8, 2), 256, 0, stream>>>(SC, emb, SP, MROW);
    // gi for merged rows -> GI[b][slot] via cdst
    k_gemm<<<dim3(24, 2), 256, 0, stream>>>(MROW, E, B, W_ih, nullptr, K3, b_ih, nullptr,
                                            1.f, GI, K3, xdst);
    // refresh <=2 pairs per b
    k_h1c<<<NWS, 256, 0, stream>>>(wlb, wlL, GI, b_hh, H1C);
    k_gemm<<<dim3(24, 4), 256, 0, stream>>>(H1C, E, NWS, W_hh, nullptr, K3, b_hh, nullptr,
                                            1.f, GHC, K3, nullptr);
    k_pairc<<<NWS, 256, 0, stream>>>(wlb, wlL, wlR, GI, GHC, H1C, w_fc, b_fc, PAIR, SCR);
  }

  // ---- final: L==2 -> h2 == PAIR[b][pos[0]]; attention, loss col 15 ----
  k_finsel<<<B, 256, 0, stream>>>(PAIR, pos, SP);
  k_gemm<<<dim3(16, 2), 256, 0, stream>>>(SP, E, B, Wq, Wk, 1024, bq, bk, 1.f,
                                          QK, 1024, nullptr);
  k_gemm<<<dim3(16, 2), 256, 0, stream>>>(QK, 1024, B, KREL, nullptr, R, nullptr, nullptr,
                                          SCALE, SC, R + 1, nullptr);
  k_softmax<<<B, 256, 0, stream>>>(SC, QK, LOSS, 15, 0);
  k_writeout<<<(B * (R + 1) + B * 16 + 255) / 256, 256, 0, stream>>>(SC, LOSS, out);
}

// Round 5
// 2363.995 us; speedup vs baseline: 1.8479x; 1.8380x over previous
//
#include <hip/hip_runtime.h>
#include <hip/hip_bf16.h>

#define B 128
#define S 16
#define E 512
#define R 1000
#define K3 1536
#define NW0 1920   // init worklist: 128 b * 15 pairs
#define NWS 256    // per-step worklist: 128 b * 2 entries
#define NSLC 8     // K-slices for merged gemm (1000/8 = 125 exact)
#define SCALE 0.04419417382415922f

static __device__ __forceinline__ float sigm(float x) { return 1.f / (1.f + expf(-x)); }

// ---------- block reductions (256 threads) ----------
static __device__ __forceinline__ float brsum(float v, float* sb) {
  int tid = threadIdx.x;
  sb[tid] = v; __syncthreads();
  for (int s = 128; s > 0; s >>= 1) {
    if (tid < s) sb[tid] += sb[tid + s];
    __syncthreads();
  }
  float r = sb[0]; __syncthreads();
  return r;
}
static __device__ __forceinline__ float brmax(float v, float* sb) {
  int tid = threadIdx.x;
  sb[tid] = v; __syncthreads();
  for (int s = 128; s > 0; s >>= 1) {
    if (tid < s) sb[tid] = fmaxf(sb[tid], sb[tid + s]);
    __syncthreads();
  }
  float r = sb[0]; __syncthreads();
  return r;
}

// ---------- embed gather ----------
__global__ __launch_bounds__(256) void k_embed(const int* __restrict__ tokens,
                                               const float* __restrict__ emb,
                                               float* __restrict__ X) {
  int idx = blockIdx.x * 256 + threadIdx.x;
  if (idx >= B * S * E) return;
  int row = idx >> 9;
  int e = idx & (E - 1);
  int tok = tokens[row];
  X[idx] = emb[(size_t)tok * E + e];
}

// ---------- init: pos identity + full worklist ----------
__global__ __launch_bounds__(256) void k_initwl(int* __restrict__ pos,
                                                int* __restrict__ wlb,
                                                int* __restrict__ wlL,
                                                int* __restrict__ wlR) {
  int idx = blockIdx.x * 256 + threadIdx.x;
  if (idx < B * 16) pos[idx] = idx & 15;
  if (idx < NW0) {
    wlb[idx] = idx / 15;
    int i = idx % 15;
    wlL[idx] = i;
    wlR[idx] = i + 1;
  }
}

// ---------- tiled GEMM, K=512 fixed, register-prefetch double-buffered:
// C[row,n] = scale * sum_k A[m*strideB + k] * Wsel[n][k] + bias_sel[n]
// Wsel = (W2 && n>=512) ? W2[n-512] : W1[n]; row = cdst ? cdst[m] : m
__global__ __launch_bounds__(256) void k_gemm(const float* __restrict__ A, int strideB, int M,
                                              const float* __restrict__ W1,
                                              const float* __restrict__ W2, int N,
                                              const float* __restrict__ b1,
                                              const float* __restrict__ b2, float scale,
                                              float* __restrict__ C, int ldc,
                                              const int* __restrict__ cdst) {
  __shared__ float As[16][64];
  __shared__ float Ws[16][64];
  int tid = threadIdx.x;
  int mBase = blockIdx.y * 64;
  int nBase = blockIdx.x * 64;
  int tx = tid & 15, ty = tid >> 4;
  int li = tid & 63;
  int lk = (tid >> 6) * 4;
  float acc[4][4] = {{0.f,0.f,0.f,0.f},{0.f,0.f,0.f,0.f},{0.f,0.f,0.f,0.f},{0.f,0.f,0.f,0.f}};
  int m = mBase + li;
  const float* Arow = (m < M) ? (A + (size_t)m * strideB) : nullptr;
  int n = nBase + li;
  const float* Wrow = nullptr;
  if (n < N) Wrow = (W2 && n >= 512) ? (W2 + (size_t)(n - 512) * E) : (W1 + (size_t)n * E);

  float4 av = Arow ? *(const float4*)(Arow + lk) : make_float4(0.f, 0.f, 0.f, 0.f);
  float4 wv = Wrow ? *(const float4*)(Wrow + lk) : make_float4(0.f, 0.f, 0.f, 0.f);

  for (int k0 = 0; k0 < E; k0 += 16) {
    As[lk + 0][li] = av.x; As[lk + 1][li] = av.y;
    As[lk + 2][li] = av.z; As[lk + 3][li] = av.w;
    Ws[lk + 0][li] = wv.x; Ws[lk + 1][li] = wv.y;
    Ws[lk + 2][li] = wv.z; Ws[lk + 3][li] = wv.w;
    __syncthreads();
    if (k0 + 16 < E) {  // prefetch next tile into regs; latency overlaps FMAs below
      av = Arow ? *(const float4*)(Arow + k0 + 16 + lk) : make_float4(0.f, 0.f, 0.f, 0.f);
      wv = Wrow ? *(const float4*)(Wrow + k0 + 16 + lk) : make_float4(0.f, 0.f, 0.f, 0.f);
    }
#pragma unroll
    for (int k = 0; k < 16; ++k) {
      float4 a4 = *(const float4*)&As[k][ty * 4];
      float4 w4 = *(const float4*)&Ws[k][tx * 4];
      acc[0][0] = fmaf(a4.x, w4.x, acc[0][0]); acc[0][1] = fmaf(a4.x, w4.y, acc[0][1]);
      acc[0][2] = fmaf(a4.x, w4.z, acc[0][2]); acc[0][3] = fmaf(a4.x, w4.w, acc[0][3]);
      acc[1][0] = fmaf(a4.y, w4.x, acc[1][0]); acc[1][1] = fmaf(a4.y, w4.y, acc[1][1]);
      acc[1][2] = fmaf(a4.y, w4.z, acc[1][2]); acc[1][3] = fmaf(a4.y, w4.w, acc[1][3]);
      acc[2][0] = fmaf(a4.z, w4.x, acc[2][0]); acc[2][1] = fmaf(a4.z, w4.y, acc[2][1]);
      acc[2][2] = fmaf(a4.z, w4.z, acc[2][2]); acc[2][3] = fmaf(a4.z, w4.w, acc[2][3]);
      acc[3][0] = fmaf(a4.w, w4.x, acc[3][0]); acc[3][1] = fmaf(a4.w, w4.y, acc[3][1]);
      acc[3][2] = fmaf(a4.w, w4.z, acc[3][2]); acc[3][3] = fmaf(a4.w, w4.w, acc[3][3]);
    }
    __syncthreads();
  }
#pragma unroll
  for (int r = 0; r < 4; ++r) {
    int mm = mBase + ty * 4 + r;
    if (mm >= M) continue;
    size_t crow = (size_t)(cdst ? cdst[mm] : mm) * ldc;
#pragma unroll
    for (int c = 0; c < 4; ++c) {
      int nn = nBase + tx * 4 + c;
      if (nn >= N) continue;
      float v = acc[r][c] * scale;
      if (b1) v += (b2 && nn >= 512) ? b2[nn - 512] : b1[nn];
      C[crow + nn] = v;
    }
  }
}

// ---------- h1 for worklist entries ----------
__global__ __launch_bounds__(256) void k_h1c(const int* __restrict__ wlb,
                                             const int* __restrict__ wlL,
                                             const float* __restrict__ GI,
                                             const float* __restrict__ bhh,
                                             float* __restrict__ H1C) {
  int w = blockIdx.x;
  const float* gi = GI + (size_t)(wlb[w] * 16 + wlL[w]) * K3;
  float* h = H1C + (size_t)w * E;
  for (int e = threadIdx.x; e < E; e += 256) {
    float r = sigm(gi[e] + bhh[e]);
    float z = sigm(gi[E + e] + bhh[E + e]);
    float n = tanhf(gi[2 * E + e] + r * bhh[2 * E + e]);
    h[e] = (1.f - z) * n;
  }
}

// ---------- pair + fc score for worklist entries ----------
__global__ __launch_bounds__(256) void k_pairc(const int* __restrict__ wlb,
                                               const int* __restrict__ wlL,
                                               const int* __restrict__ wlR,
                                               const float* __restrict__ GI,
                                               const float* __restrict__ GHC,
                                               const float* __restrict__ H1C,
                                               const float* __restrict__ wfc,
                                               const float* __restrict__ bfc,
                                               float* __restrict__ PAIR,
                                               float* __restrict__ SCR) {
  __shared__ float sb[256];
  int w = blockIdx.x, tid = threadIdx.x;
  int b = wlb[w], ls = wlL[w], rs = wlR[w];
  const float* gi = GI + (size_t)(b * 16 + rs) * K3;
  const float* gh = GHC + (size_t)w * K3;
  const float* h = H1C + (size_t)w * E;
  float* p = PAIR + (size_t)(b * 16 + ls) * E;
  float part = 0.f;
  for (int e = tid; e < E; e += 256) {
    float r = sigm(gi[e] + gh[e]);
    float z = sigm(gi[E + e] + gh[E + e]);
    float n = tanhf(gi[2 * E + e] + r * gh[2 * E + e]);
    float pv = (1.f - z) * n + z * h[e];
    p[e] = pv;
    part += pv * wfc[e];
  }
  float d = brsum(part, sb);
  if (tid == 0) SCR[b * 16 + ls] = sigm(d + bfc[0]);
}

// ---------- argmax + gather + pos/worklist update ----------
__global__ __launch_bounds__(256) void k_sel(const float* __restrict__ SCR,
                                             const float* __restrict__ PAIR,
                                             int* __restrict__ pos, int P,
                                             float* __restrict__ SP,
                                             int* __restrict__ xdst,
                                             int* __restrict__ wlb,
                                             int* __restrict__ wlL,
                                             int* __restrict__ wlR) {
  __shared__ int s_m;
  int b = blockIdx.x, tid = threadIdx.x;
  if (tid == 0) {
    int L = P + 1;
    int lp[16];
    for (int i = 0; i < L; ++i) lp[i] = pos[b * 16 + i];
    float best = -1e30f; int sel = 0;
    for (int i = 0; i < P; ++i) {
      float v = SCR[b * 16 + lp[i]];
      if (v > best) { best = v; sel = i; }
    }
    int r1i = (sel + 2 < L) ? sel + 2 : L - 1;
    int l1 = lp[sel], r1 = lp[r1i];
    int l0 = (sel > 0) ? lp[sel - 1] : l1;
    int r0 = (sel > 0) ? lp[sel] : r1;
    wlb[2 * b] = b;     wlL[2 * b] = l0;     wlR[2 * b] = r0;
    wlb[2 * b + 1] = b; wlL[2 * b + 1] = l1; wlR[2 * b + 1] = r1;
    xdst[b] = b * 16 + lp[sel];
    for (int i = sel + 1; i < L - 1; ++i) pos[b * 16 + i] = lp[i + 1];
    s_m = lp[sel];
  }
  __syncthreads();
  int ms = s_m;
  const float* src = PAIR + (size_t)(b * 16 + ms) * E;
  float* dst = SP + (size_t)b * E;
  for (int e = tid; e < E; e += 256) dst[e] = src[e];
}

// ---------- final gather: SP = PAIR[b][pos[0]] ----------
__global__ __launch_bounds__(256) void k_finsel(const float* __restrict__ PAIR,
                                                const int* __restrict__ pos,
                                                float* __restrict__ SP) {
  int b = blockIdx.x;
  const float* src = PAIR + (size_t)(b * 16 + pos[b * 16]) * E;
  float* dst = SP + (size_t)b * E;
  for (int e = threadIdx.x; e < E; e += 256) dst[e] = src[e];
}

// ---------- softmax / entropy; prob in place; MROW base = probR*SP ----------
__global__ __launch_bounds__(256) void k_softmax(float* __restrict__ SC,
                                                 const float* __restrict__ QK,
                                                 const float* __restrict__ SP,
                                                 float* __restrict__ MROW,
                                                 float* __restrict__ LOSS, int t, int writeProb) {
  __shared__ float sb[256];
  int b = blockIdx.x, tid = threadIdx.x;
  const float* q = QK + (size_t)b * 1024;
  const float* kl = q + 512;
  float part = 0.f;
  for (int e = tid; e < E; e += 256) part += q[e] * kl[e];
  float last = brsum(part, sb) * SCALE;
  float* s = SC + (size_t)b * (R + 1);
  if (tid == 0) s[R] = last;
  __syncthreads();
  float mx = -1e30f;
  for (int j = tid; j <= R; j += 256) mx = fmaxf(mx, s[j]);
  mx = brmax(mx, sb);
  float z = 0.f, s1 = 0.f;
  for (int j = tid; j <= R; j += 256) {
    float sj = s[j];
    float e = expf(sj - mx);
    z += e; s1 += e * sj;
  }
  z = brsum(z, sb);
  s1 = brsum(s1, sb);
  if (tid == 0) LOSS[b * 16 + t] = mx + logf(z) - s1 / z;
  if (writeProb) {
    float inv = 1.f / z;
    for (int j = tid; j <= R; j += 256) s[j] = expf(s[j] - mx) * inv;
    float pr = expf(last - mx) * inv;
    for (int e = tid; e < E; e += 256) MROW[(size_t)b * E + e] = pr * SP[(size_t)b * E + e];
  }
}

// ---------- merged gemm, split-K: PART[slice] += prob[:,kslice] @ emb[kslice,:]
__global__ __launch_bounds__(256) void k_merged(const float* __restrict__ SC,
                                                const float* __restrict__ emb,
                                                float* __restrict__ PART) {
  __shared__ float As[16][64];
  __shared__ float Ws[16][64];
  int tid = threadIdx.x;
  int nBase = blockIdx.x * 64;
  int mBase = blockIdx.y * 64;
  int slice = blockIdx.z;
  int kbeg = slice * 125, kend = kbeg + 125;
  int tx = tid & 15, ty = tid >> 4;
  int li = tid & 63;
  int lk = (tid >> 6) * 4;
  int wr = tid >> 6;
  float acc[4][4] = {{0.f,0.f,0.f,0.f},{0.f,0.f,0.f,0.f},{0.f,0.f,0.f,0.f},{0.f,0.f,0.f,0.f}};
  int m = mBase + li;
  for (int k0 = kbeg; k0 < kend; k0 += 16) {
    float a4[4];
#pragma unroll
    for (int j = 0; j < 4; ++j) {
      int kk = k0 + lk + j;
      a4[j] = (kk < kend) ? SC[(size_t)m * (R + 1) + kk] : 0.f;
    }
    As[lk + 0][li] = a4[0]; As[lk + 1][li] = a4[1];
    As[lk + 2][li] = a4[2]; As[lk + 3][li] = a4[3];
#pragma unroll
    for (int j = 0; j < 4; ++j) {
      int kk = k0 + wr * 4 + j;
      Ws[wr * 4 + j][li] = (kk < kend) ? emb[(size_t)kk * E + nBase + li] : 0.f;
    }
    __syncthreads();
#pragma unroll
    for (int k = 0; k < 16; ++k) {
      float4 av = *(const float4*)&As[k][ty * 4];
      float4 wv = *(const float4*)&Ws[k][tx * 4];
      acc[0][0] = fmaf(av.x, wv.x, acc[0][0]); acc[0][1] = fmaf(av.x, wv.y, acc[0][1]);
      acc[0][2] = fmaf(av.x, wv.z, acc[0][2]); acc[0][3] = fmaf(av.x, wv.w, acc[0][3]);
      acc[1][0] = fmaf(av.y, wv.x, acc[1][0]); acc[1][1] = fmaf(av.y, wv.y, acc[1][1]);
      acc[1][2] = fmaf(av.y, wv.z, acc[1][2]); acc[1][3] = fmaf(av.y, wv.w, acc[1][3]);
      acc[2][0] = fmaf(av.z, wv.x, acc[2][0]); acc[2][1] = fmaf(av.z, wv.y, acc[2][1]);
      acc[2][2] = fmaf(av.z, wv.z, acc[2][2]); acc[2][3] = fmaf(av.z, wv.w, acc[2][3]);
      acc[3][0] = fmaf(av.w, wv.x, acc[3][0]); acc[3][1] = fmaf(av.w, wv.y, acc[3][1]);
      acc[3][2] = fmaf(av.w, wv.z, acc[3][2]); acc[3][3] = fmaf(av.w, wv.w, acc[3][3]);
    }
    __syncthreads();
  }
  float* pt = PART + ((size_t)slice * B) * E;
#pragma unroll
  for (int r = 0; r < 4; ++r) {
    int mm = mBase + ty * 4 + r;
#pragma unroll
    for (int c = 0; c < 4; ++c) {
      int nn = nBase + tx * 4 + c;
      pt[(size_t)mm * E + nn] = acc[r][c];
    }
  }
}

// ---------- reduce partials onto MROW base ----------
__global__ __launch_bounds__(256) void k_red(const float* __restrict__ PART,
                                             float* __restrict__ MROW) {
  int m = blockIdx.x;
  for (int n = threadIdx.x; n < E; n += 256) {
    float v = MROW[(size_t)m * E + n];
#pragma unroll
    for (int s = 0; s < NSLC; ++s) v += PART[((size_t)s * B + m) * E + n];
    MROW[(size_t)m * E + n] = v;
  }
}

// ---------- final write (fp32 out: scores then losses, flat) ----------
__global__ __launch_bounds__(256) void k_writeout(const float* __restrict__ SC,
                                                  const float* __restrict__ LOSS,
                                                  float* __restrict__ out) {
  int idx = blockIdx.x * 256 + threadIdx.x;
  const int NS = B * (R + 1);
  if (idx < NS) {
    out[idx] = SC[idx];
  } else if (idx < NS + B * 16) {
    int r = idx - NS;
    int t = r & 15;
    out[idx] = (t == 14) ? 0.f : LOSS[r];
  }
}

extern "C" void kernel_launch(void* const* d_in, const int* in_sizes, int n_in,
                              void* d_out, int out_size, void* d_ws, size_t ws_size,
                              hipStream_t stream) {
  (void)in_sizes; (void)n_in; (void)out_size; (void)ws_size;
  const int* tokens = (const int*)d_in[0];
  const float* emb = (const float*)d_in[1];
  const float* W_ih = (const float*)d_in[2];
  const float* W_hh = (const float*)d_in[3];
  const float* b_ih = (const float*)d_in[4];
  const float* b_hh = (const float*)d_in[5];
  const float* w_fc = (const float*)d_in[6];
  const float* b_fc = (const float*)d_in[7];
  const float* Wq = (const float*)d_in[8];
  const float* bq = (const float*)d_in[9];
  const float* Wk = (const float*)d_in[10];
  const float* bk = (const float*)d_in[11];
  float* out = (float*)d_out;

  float* ws = (float*)d_ws;
  size_t o = 0;
  float* X = ws + o;     o += (size_t)B * 16 * E;
  float* GI = ws + o;    o += (size_t)B * 16 * K3;
  float* PAIR = ws + o;  o += (size_t)B * 16 * E;
  float* SCR = ws + o;   o += (size_t)B * 16;
  float* H1C = ws + o;   o += (size_t)NW0 * E;
  float* GHC = ws + o;   o += (size_t)NW0 * K3;
  float* KREL = ws + o;  o += (size_t)R * E;
  float* QK = ws + o;    o += (size_t)B * 1024;
  float* SP = ws + o;    o += (size_t)B * E;
  float* SC = ws + o;    o += (size_t)B * (R + 1);
  float* MROW = ws + o;  o += (size_t)B * E;
  float* PART = ws + o;  o += (size_t)NSLC * B * E;
  float* LOSS = ws + o;  o += (size_t)B * 16;
  int* pos = (int*)(ws + o);  o += B * 16;
  int* wlb = (int*)(ws + o);  o += NW0;
  int* wlL = (int*)(ws + o);  o += NW0;
  int* wlR = (int*)(ws + o);  o += NW0;
  int* xdst = (int*)(ws + o); o += B;

  // ---- setup ----
  k_embed<<<(B * S * E + 255) / 256, 256, 0, stream>>>(tokens, emb, X);
  k_initwl<<<8, 256, 0, stream>>>(pos, wlb, wlL, wlR);
  k_gemm<<<dim3(8, 16), 256, 0, stream>>>(emb, E, R, Wk, nullptr, E, bk, nullptr, 1.f,
                                          KREL, E, nullptr);
  k_gemm<<<dim3(24, 32), 256, 0, stream>>>(X, E, B * 16, W_ih, nullptr, K3, b_ih, nullptr,
                                           1.f, GI, K3, nullptr);
  k_h1c<<<NW0, 256, 0, stream>>>(wlb, wlL, GI, b_hh, H1C);
  k_gemm<<<dim3(24, 30), 256, 0, stream>>>(H1C, E, NW0, W_hh, nullptr, K3, b_hh, nullptr,
                                           1.f, GHC, K3, nullptr);
  k_pairc<<<NW0, 256, 0, stream>>>(wlb, wlL, wlR, GI, GHC, H1C, w_fc, b_fc, PAIR, SCR);

  // ---- 14 merge steps ----
  for (int t = 0; t < 14; ++t) {
    int P = 15 - t;
    k_sel<<<B, 256, 0, stream>>>(SCR, PAIR, pos, P, SP, xdst, wlb, wlL, wlR);
    k_gemm<<<dim3(16, 2), 256, 0, stream>>>(SP, E, B, Wq, Wk, 1024, bq, bk, 1.f,
                                            QK, 1024, nullptr);
    k_gemm<<<dim3(16, 2), 256, 0, stream>>>(QK, 1024, B, KREL, nullptr, R, nullptr, nullptr,
                                            SCALE, SC, R + 1, nullptr);
    k_softmax<<<B, 256, 0, stream>>>(SC, QK, SP, MROW, LOSS, t, 1);
    k_merged<<<dim3(8, 2, NSLC), 256, 0, stream>>>(SC, emb, PART);
    k_red<<<B, 256, 0, stream>>>(PART, MROW);
    k_gemm<<<dim3(24, 2), 256, 0, stream>>>(MROW, E, B, W_ih, nullptr, K3, b_ih, nullptr,
                                            1.f, GI, K3, xdst);
    k_h1c<<<NWS, 256, 0, stream>>>(wlb, wlL, GI, b_hh, H1C);
    k_gemm<<<dim3(24, 4), 256, 0, stream>>>(H1C, E, NWS, W_hh, nullptr, K3, b_hh, nullptr,
                                            1.f, GHC, K3, nullptr);
    k_pairc<<<NWS, 256, 0, stream>>>(wlb, wlL, wlR, GI, GHC, H1C, w_fc, b_fc, PAIR, SCR);
  }

  // ---- final: L==2 -> h2 == PAIR[b][pos[0]]; attention, loss col 15 ----
  k_finsel<<<B, 256, 0, stream>>>(PAIR, pos, SP);
  k_gemm<<<dim3(16, 2), 256, 0, stream>>>(SP, E, B, Wq, Wk, 1024, bq, bk, 1.f,
                                          QK, 1024, nullptr);
  k_gemm<<<dim3(16, 2), 256, 0, stream>>>(QK, 1024, B, KREL, nullptr, R, nullptr, nullptr,
                                          SCALE, SC, R + 1, nullptr);
  k_softmax<<<B, 256, 0, stream>>>(SC, QK, SP, MROW, LOSS, 15, 0);
  k_writeout<<<(B * (R + 1) + B * 16 + 255) / 256, 256, 0, stream>>>(SC, LOSS, out);
}